// Round 9
// baseline (381.326 us; speedup 1.0000x reference)
//
#include <hip/hip_runtime.h>

// Problem constants
#define BB 8
#define NN 4096
#define CC 128
#define RR 16
#define EE 65536
#define NNODES 32768
#define NEDGES 524288
#define BCAP  48                 // per-dst bucket capacity (Poisson16: P(ovf)~2e-6 over all nodes)
#define SCE   15                 // entries per srt row; slot 0 holds the count
#define NT    32                 // nodes per agg block (8 threads/node) — R4-verified best
#define ALP   136                // A-tile LDS row stride (shorts): 272B, 16B-aligned
#define NBLK  1024               // grid: 4 blocks/CU, co-resident by construction

typedef unsigned short ushort_t;
typedef short bf16x8 __attribute__((ext_vector_type(8)));
typedef float f32x4 __attribute__((ext_vector_type(4)));

__device__ __forceinline__ unsigned short f2b(float f) {
    unsigned u = __builtin_bit_cast(unsigned, f);
    unsigned r = (u + 0x7fffu + ((u >> 16) & 1u)) >> 16;   // RNE
    return (unsigned short)r;
}
__device__ __forceinline__ float b2f(unsigned short s) {
    return __builtin_bit_cast(float, (unsigned)s << 16);
}
__device__ __forceinline__ float ldf(const void* p, int j, int isbf) {
    return isbf ? b2f(((const ushort_t*)p)[j]) : ((const float*)p)[j];
}
__device__ __forceinline__ int ldi(const int* p, int j, int is64) {
    return p[j << is64];
}
// v_cvt_pk_bf16_f32: D = {hi=bf16(s1), lo=bf16(s0)}, RNE
__device__ __forceinline__ unsigned cvtpk(float lo, float hi) {
    unsigned r;
    asm("v_cvt_pk_bf16_f32 %0, %1, %2" : "=v"(r) : "v"(lo), "v"(hi));
    return r;
}

// sum 8 bf16 (one uint4) into s[sb..sb+7] as fp32
#define GSUM8(u, sb) do { \
    s[sb+0] += __builtin_bit_cast(float, (u).x << 16); \
    s[sb+1] += __builtin_bit_cast(float, (u).x & 0xffff0000u); \
    s[sb+2] += __builtin_bit_cast(float, (u).y << 16); \
    s[sb+3] += __builtin_bit_cast(float, (u).y & 0xffff0000u); \
    s[sb+4] += __builtin_bit_cast(float, (u).z << 16); \
    s[sb+5] += __builtin_bit_cast(float, (u).z & 0xffff0000u); \
    s[sb+6] += __builtin_bit_cast(float, (u).w << 16); \
    s[sb+7] += __builtin_bit_cast(float, (u).w & 0xffff0000u); \
} while (0)

struct AggSM {
    int scnt[NT * 16];                 // 2048 B
    ushort_t srt[NT * 16 * 16];        // 16384 B ([row][0..] entries; counts folded after sort)
    ushort_t A[2][NT * ALP];           // 17408 B (double-buffered A-tile)
    float red[NT][5];                  // 640 B
};
union SM {
    AggSM agg;                         // 36480 B -> 4 blocks/CU
    ushort_t Ls[128 * 40];             // 10240 B (WT3 transpose tile)
};

// ---- manual grid barrier: all NBLK blocks are co-resident (4/CU, LDS/VGPR/wave
// margins verified). Device-scope atomics + agent fences handle XCD L2s. ----
__device__ __forceinline__ void gbar(int* bar, int idx) {
    __syncthreads();
    if (threadIdx.x == 0) {
        __threadfence();                               // publish prior writes
        atomicAdd(&bar[idx * 16], 1);
        while (atomicAdd(&bar[idx * 16], 0) < NBLK)
            __builtin_amdgcn_s_sleep(8);
        __threadfence();                               // acquire: invalidate L1
    }
    __syncthreads();
}

// ---------- phase helpers ----------
__device__ __forceinline__ void do_cast(int bx, int t, const void* x,
                                        ushort_t* Xb, int isbf) {
    int base = (bx & 7) * 65536 + (bx >> 3) * 512 + t; // batch-affine
    #pragma unroll
    for (int i = 0; i < 2; ++i) {
        int tid = base + i * 256;                      // < 524288 uint4
        if (isbf) {
            ((uint4*)Xb)[tid] = ((const uint4*)x)[tid];
        } else {
            const float4* xf = (const float4*)x;
            float4 a = xf[2 * tid], b = xf[2 * tid + 1];
            ushort4 o0, o1;
            o0.x = f2b(a.x); o0.y = f2b(a.y); o0.z = f2b(a.z); o0.w = f2b(a.w);
            o1.x = f2b(b.x); o1.y = f2b(b.y); o1.z = f2b(b.z); o1.w = f2b(b.w);
            ((ushort4*)Xb)[2 * tid] = o0; ((ushort4*)Xb)[2 * tid + 1] = o1;
        }
    }
}

__device__ __forceinline__ void do_wt3(int mb, int t, ushort_t* Ls,
                                       const void* relw, const void* rootw,
                                       ushort_t* WT3, int isbf) {
    // fragment-major swizzle: each MFMA B-frag = ONE contiguous 1KB wave-load
    int mat = mb >> 2, chunk = mb & 3;                 // pass, 32-k chunk (=ks)
    const void* src = (mat == 16) ? rootw : relw;
    int soff = (mat == 16) ? 0 : mat * 16384;
    int k0 = chunk * 32;
    #pragma unroll
    for (int i = 0; i < 16; ++i) {                     // coalesced read: c fast
        int idx = t + i * 256;                         // < 4096
        int k = idx >> 7, c = idx & 127;
        Ls[c * 40 + k] = f2b(ldf(src, soff + (k0 + k) * 128 + c, isbf));
    }
    __syncthreads();
    #pragma unroll
    for (int i = 0; i < 2; ++i) {                      // contiguous 1KB per frag
        int idx = t + i * 256;                         // < 512 = 8 cg x 64 lanes
        int cg = idx >> 6, lane = idx & 63;
        int lrow = lane & 15, lq = lane >> 4;
        uint4 v = *(const uint4*)(&Ls[(cg * 16 + lrow) * 40 + lq * 8]);
        *(uint4*)(WT3 + ((size_t)((mat * 4 + chunk) * 8 + cg)) * 512 + lane * 8) = v;
    }
}

__device__ __forceinline__ void do_edges(int bx, int t, const int* ei, const int* et,
                                         int* dcnt, int* bucket, int w64i, int w64t) {
    int b = bx & 7;                                    // batch -> XCD affinity
    int e0 = (bx >> 3) * 512 + t, e1 = e0 + 256;       // < EE
    int src0 = ldi(ei, (b * 2) * EE + e0, w64i);
    int dst0 = ldi(ei, (b * 2 + 1) * EE + e0, w64i);
    int r0 = ldi(et, (b << 16) + e0, w64t);
    int src1 = ldi(ei, (b * 2) * EE + e1, w64i);
    int dst1 = ldi(ei, (b * 2 + 1) * EE + e1, w64i);
    int r1 = ldi(et, (b << 16) + e1, w64t);
    int gd0 = (b << 12) + dst0, gd1 = (b << 12) + dst1;
    int p0 = atomicAdd(&dcnt[gd0 << 4], 1);            // line-padded counters
    int p1 = atomicAdd(&dcnt[gd1 << 4], 1);
    if (p0 < BCAP) bucket[gd0 * BCAP + p0] = (((b << 12) + src0) << 4) | r0;
    if (p1 < BCAP) bucket[gd1 * BCAP + p1] = (((b << 12) + src1) << 4) | r1;
}

// ---------- agg phase (R4-verified structure: NT=32, dbuf A, 49us standalone) ----------
__device__ __forceinline__ void do_agg(int bx, int t, AggSM& sm,
                                       const ushort_t* Xb, const ushort_t* WT3,
                                       const int* dcnt, const int* bucket,
                                       const void* bias, const void* linw,
                                       const void* linb, void* out, int isbf) {
    int n0 = (bx & 7) * NN + (bx >> 3) * NT;

    sm.scnt[t] = 0; sm.scnt[256 + t] = 0;
    __syncthreads();

    int nsub = t >> 3, tsub = t & 7;           // node-in-tile, 8 threads/node
    int gn = n0 + nsub;
    int offA = tsub * 8, offB = 64 + tsub * 8; // two 8-col octets per thread
    int nc = dcnt[gn << 4]; if (nc > BCAP) nc = BCAP;
    const int* bk = bucket + gn * BCAP;
    for (int j = tsub; j < nc; j += 8) {
        int v = bk[j];
        int row = (nsub << 4) + (v & 15);
        int pos = atomicAdd(&sm.scnt[row], 1);
        if (pos < SCE)
            sm.srt[(row << 4) + 1 + pos] = (ushort_t)((unsigned)v >> 4);
    }
    __syncthreads();
    sm.srt[t << 4] = (ushort_t)sm.scnt[t];     // fold counts into srt slot 0
    sm.srt[(t + 256) << 4] = (ushort_t)sm.scnt[t + 256];
    __syncthreads();

    int wave = t >> 6, lane = t & 63, lrow = lane & 15, lq = lane >> 4;
    f32x4 acc[2][2] = {};

    // prologue: build A[0] for relation 0 (serial, once)
    {
        int row = nsub << 4;
        uint4 q0 = *(const uint4*)(&sm.srt[row << 4]);
        int cf = q0.x & 0xffffu; int ce = cf > SCE ? SCE : cf;
        float s[16];
        #pragma unroll
        for (int j = 0; j < 16; ++j) s[j] = 0.f;
        for (int e = 0; e < ce; ++e) {
            int gs = sm.srt[(row << 4) + 1 + e];
            const ushort_t* xr = Xb + (size_t)gs * 128;
            uint4 ua = *(const uint4*)(xr + offA), ub = *(const uint4*)(xr + offB);
            GSUM8(ua, 0); GSUM8(ub, 8);
        }
        float w = (cf > 0) ? 1.0f / (float)cf : 0.f;
        uint4 va, vb;
        va.x = cvtpk(s[0] * w, s[1] * w);   va.y = cvtpk(s[2] * w, s[3] * w);
        va.z = cvtpk(s[4] * w, s[5] * w);   va.w = cvtpk(s[6] * w, s[7] * w);
        vb.x = cvtpk(s[8] * w, s[9] * w);   vb.y = cvtpk(s[10] * w, s[11] * w);
        vb.z = cvtpk(s[12] * w, s[13] * w); vb.w = cvtpk(s[14] * w, s[15] * w);
        *(uint4*)(&sm.A[0][nsub * ALP + offA]) = va;
        *(uint4*)(&sm.A[0][nsub * ALP + offB]) = vb;
    }
    __syncthreads();

    for (int p = 0; p < 17; ++p) {
        int np = p + 1;
        // ---- stage pass np: count+4 entries via one ds_read_b128 ----
        uint4 r0a, r0b, r1a, r1b, r2a, r2b, r3a, r3b;
        int cf = 0, ce = 0, row = 0;
        if (np < 16) {
            row = (nsub << 4) + np;
            uint4 q0 = *(const uint4*)(&sm.srt[row << 4]);
            cf = q0.x & 0xffffu; ce = cf > SCE ? SCE : cf;
            int e0 = q0.x >> 16, e1 = q0.y & 0xffffu, e2 = q0.y >> 16, e3 = q0.z & 0xffffu;
            if (ce > 0) { const ushort_t* xr = Xb + (size_t)e0 * 128; r0a = *(const uint4*)(xr + offA); r0b = *(const uint4*)(xr + offB); }
            if (ce > 1) { const ushort_t* xr = Xb + (size_t)e1 * 128; r1a = *(const uint4*)(xr + offA); r1b = *(const uint4*)(xr + offB); }
            if (ce > 2) { const ushort_t* xr = Xb + (size_t)e2 * 128; r2a = *(const uint4*)(xr + offA); r2b = *(const uint4*)(xr + offB); }
            if (ce > 3) { const ushort_t* xr = Xb + (size_t)e3 * 128; r3a = *(const uint4*)(xr + offA); r3b = *(const uint4*)(xr + offB); }
        } else if (np == 16) {             // root pass: own row
            const ushort_t* xr = Xb + (size_t)gn * 128;
            r0a = *(const uint4*)(xr + offA); r0b = *(const uint4*)(xr + offB);
        }
        // ---- MFMA on A[p&1]; B-frags = contiguous 1KB loads from WT3 ----
        const ushort_t* Ap = sm.A[p & 1];
        const ushort_t* bw = WT3 + (size_t)p * 16384 + (wave * 2) * 512 + lane * 8;
        __builtin_amdgcn_s_setprio(1);
        #pragma unroll
        for (int ks = 0; ks < 4; ++ks) {
            int k0 = ks * 32 + lq * 8;
            bf16x8 a0 = *(const bf16x8*)(&Ap[lrow * ALP + k0]);
            bf16x8 a1 = *(const bf16x8*)(&Ap[(16 + lrow) * ALP + k0]);
            bf16x8 b0 = *(const bf16x8*)(bw + ks * 4096);
            bf16x8 b1 = *(const bf16x8*)(bw + ks * 4096 + 512);
            acc[0][0] = __builtin_amdgcn_mfma_f32_16x16x32_bf16(a0, b0, acc[0][0], 0, 0, 0);
            acc[0][1] = __builtin_amdgcn_mfma_f32_16x16x32_bf16(a0, b1, acc[0][1], 0, 0, 0);
            acc[1][0] = __builtin_amdgcn_mfma_f32_16x16x32_bf16(a1, b0, acc[1][0], 0, 0, 0);
            acc[1][1] = __builtin_amdgcn_mfma_f32_16x16x32_bf16(a1, b1, acc[1][1], 0, 0, 0);
        }
        __builtin_amdgcn_s_setprio(0);
        // ---- finish sums, pack A[np&1] ----
        if (np < 16) {
            float s[16];
            #pragma unroll
            for (int j = 0; j < 16; ++j) s[j] = 0.f;
            if (ce > 0) { GSUM8(r0a, 0); GSUM8(r0b, 8); }
            if (ce > 1) { GSUM8(r1a, 0); GSUM8(r1b, 8); }
            if (ce > 2) { GSUM8(r2a, 0); GSUM8(r2b, 8); }
            if (ce > 3) { GSUM8(r3a, 0); GSUM8(r3b, 8); }
            if (ce > 4) {                  // rare tail (P~0.4% per list)
                for (int e4 = 4; e4 < ce; ++e4) {
                    int gs = sm.srt[(row << 4) + 1 + e4];
                    const ushort_t* xr = Xb + (size_t)gs * 128;
                    uint4 ta = *(const uint4*)(xr + offA), tb = *(const uint4*)(xr + offB);
                    GSUM8(ta, 0); GSUM8(tb, 8);
                }
            }
            float w = (cf > 0) ? 1.0f / (float)cf : 0.f;
            uint4 va, vb;
            va.x = cvtpk(s[0] * w, s[1] * w);   va.y = cvtpk(s[2] * w, s[3] * w);
            va.z = cvtpk(s[4] * w, s[5] * w);   va.w = cvtpk(s[6] * w, s[7] * w);
            vb.x = cvtpk(s[8] * w, s[9] * w);   vb.y = cvtpk(s[10] * w, s[11] * w);
            vb.z = cvtpk(s[12] * w, s[13] * w); vb.w = cvtpk(s[14] * w, s[15] * w);
            *(uint4*)(&sm.A[np & 1][nsub * ALP + offA]) = va;
            *(uint4*)(&sm.A[np & 1][nsub * ALP + offB]) = vb;
        } else if (np == 16) {
            *(uint4*)(&sm.A[np & 1][nsub * ALP + offA]) = r0a;
            *(uint4*)(&sm.A[np & 1][nsub * ALP + offB]) = r0b;
        }
        if (p < 16) __syncthreads();
    }

    // Epilogue: out[n][c] = relu(acc + bias[c]) * linw[c], reduce over c
    int wn = wave << 5;
    int c0 = wn + lrow, c1 = wn + 16 + lrow;
    float bi0 = ldf(bias, c0, isbf), bi1 = ldf(bias, c1, isbf);
    float lw0 = ldf(linw, c0, isbf), lw1 = ldf(linw, c1, isbf);
    #pragma unroll
    for (int mi = 0; mi < 2; ++mi)
        #pragma unroll
        for (int rg = 0; rg < 4; ++rg) {
            float p = fmaxf(acc[mi][0][rg] + bi0, 0.f) * lw0
                    + fmaxf(acc[mi][1][rg] + bi1, 0.f) * lw1;
            p += __shfl_xor(p, 1, 64);
            p += __shfl_xor(p, 2, 64);
            p += __shfl_xor(p, 4, 64);
            p += __shfl_xor(p, 8, 64);
            if (lrow == 0) sm.red[mi * 16 + lq * 4 + rg][wave] = p;
        }
    __syncthreads();
    if (t < NT) {
        float res = sm.red[t][0] + sm.red[t][1] + sm.red[t][2] + sm.red[t][3]
                  + ldf(linb, 0, isbf);
        if (isbf) ((ushort_t*)out)[n0 + t] = f2b(res);
        else      ((float*)out)[n0 + t] = res;
    }
}

// ---------- fused kernel, plain launch + manual grid barrier ----------
// 1024 blocks x 256 = 4 blocks/CU co-resident (LDS 36.5KB->4/CU, VGPR<=128/wave
// at 16 waves/CU, 16 of 32 wave slots). phase0: zero dcnt + cast + WT3 | gbar |
// phase1: edge bucketing | gbar | phase2: aggregate-first mean+GEMM+score.
__global__ __launch_bounds__(256, 4) void fused_k(const void* __restrict__ x,
                                                  const void* __restrict__ relw,
                                                  const void* __restrict__ rootw,
                                                  const int* __restrict__ ei,
                                                  const int* __restrict__ et,
                                                  ushort_t* __restrict__ Xb,
                                                  ushort_t* __restrict__ WT3,
                                                  int* __restrict__ dcnt,
                                                  int* __restrict__ bucket,
                                                  int* __restrict__ bar,
                                                  const void* __restrict__ bias,
                                                  const void* __restrict__ linw,
                                                  const void* __restrict__ linb,
                                                  void* __restrict__ out,
                                                  int isbf, int w64i, int w64t) {
    __shared__ SM sm;
    int bx = blockIdx.x, t = threadIdx.x;

    // ---- phase 0: zero dcnt + cast + WT3 swizzle ----
    if (t < 128) ((uint4*)dcnt)[(bx << 7) + t] = make_uint4(0, 0, 0, 0);
    do_cast(bx, t, x, Xb, isbf);
    if (bx < 68) do_wt3(bx, t, sm.Ls, relw, rootw, WT3, isbf);
    gbar(bar, 0);

    // ---- phase 1: edge bucketing ----
    do_edges(bx, t, ei, et, dcnt, bucket, w64i, w64t);
    gbar(bar, 1);

    // ---- phase 2: aggregate ----
    do_agg(bx, t, sm.agg, Xb, WT3, dcnt, bucket, bias, linw, linb, out, isbf);
}

extern "C" void kernel_launch(void* const* d_in, const int* in_sizes, int n_in,
                              void* d_out, int out_size, void* d_ws, size_t ws_size,
                              hipStream_t stream) {
    const void* x     = d_in[0];
    const int*  ei    = (const int*)d_in[1];
    const int*  et    = (const int*)d_in[2];
    const void* relw  = d_in[3];
    const void* rootw = d_in[4];
    const void* bias  = d_in[5];
    const void* linw  = d_in[6];
    const void* linb  = d_in[7];

    // Host-side dtype dispatch from input byte sizes
    int isbf = (in_sizes[0] == BB * NN * CC * 2);        // bf16 features
    int w64i = (in_sizes[1] == BB * 2 * EE * 8);         // int64 edge_index
    int w64t = (in_sizes[2] == BB * EE * 8);             // int64 edge_type

    const size_t WS_NEED = 17334528;
    if (ws_size < WS_NEED) return;

    char* ws = (char*)d_ws;
    ushort_t* Xb     = (ushort_t*)(ws);                       //  8,388,608
    ushort_t* WT3    = (ushort_t*)(ws + 8388608);             //    557,056
    int*      dcnt   = (int*)(ws + 8945664);                  //  2,097,152 (line-padded)
    int*      bucket = (int*)(ws + 11042816);                 //  6,291,456 (32768*48*4)
    int*      bar    = (int*)(ws + 17334272);                 //        256 (2 padded counters)

    hipMemsetAsync(bar, 0, 256, stream);
    fused_k<<<NBLK, 256, 0, stream>>>(x, relw, rootw, ei, et, Xb, WT3, dcnt, bucket,
                                      bar, bias, linw, linb, d_out, isbf, w64i, w64t);
}

// Round 10
// 153.645 us; speedup vs baseline: 2.4819x; 2.4819x over previous
//
#include <hip/hip_runtime.h>

// Problem constants
#define BB 8
#define NN 4096
#define CC 128
#define RR 16
#define EE 65536
#define NNODES 32768
#define NEDGES 524288
#define BCAP  48                 // per-dst bucket capacity (Poisson16: P(ovf)~2e-6 over all nodes)
#define SCE   15                 // entries per srt row; slot 0 holds the count
#define NT    32                 // nodes per agg block — R4-verified best
#define ALP   136                // A-tile LDS row stride (shorts): 272B, 16B-aligned

typedef unsigned short ushort_t;
typedef short bf16x8 __attribute__((ext_vector_type(8)));
typedef float f32x4 __attribute__((ext_vector_type(4)));

__device__ __forceinline__ unsigned short f2b(float f) {
    unsigned u = __builtin_bit_cast(unsigned, f);
    unsigned r = (u + 0x7fffu + ((u >> 16) & 1u)) >> 16;   // RNE
    return (unsigned short)r;
}
__device__ __forceinline__ float b2f(unsigned short s) {
    return __builtin_bit_cast(float, (unsigned)s << 16);
}
__device__ __forceinline__ float ldf(const void* p, int j, int isbf) {
    return isbf ? b2f(((const ushort_t*)p)[j]) : ((const float*)p)[j];
}
__device__ __forceinline__ int ldi(const int* p, int j, int is64) {
    return p[j << is64];
}
// v_cvt_pk_bf16_f32: D = {hi=bf16(s1), lo=bf16(s0)}, RNE
__device__ __forceinline__ unsigned cvtpk(float lo, float hi) {
    unsigned r;
    asm("v_cvt_pk_bf16_f32 %0, %1, %2" : "=v"(r) : "v"(lo), "v"(hi));
    return r;
}

// sum 8 bf16 (one uint4) into s[sb..sb+7] as fp32
#define GSUM8(u, sb) do { \
    s[sb+0] += __builtin_bit_cast(float, (u).x << 16); \
    s[sb+1] += __builtin_bit_cast(float, (u).x & 0xffff0000u); \
    s[sb+2] += __builtin_bit_cast(float, (u).y << 16); \
    s[sb+3] += __builtin_bit_cast(float, (u).y & 0xffff0000u); \
    s[sb+4] += __builtin_bit_cast(float, (u).z << 16); \
    s[sb+5] += __builtin_bit_cast(float, (u).z & 0xffff0000u); \
    s[sb+6] += __builtin_bit_cast(float, (u).w << 16); \
    s[sb+7] += __builtin_bit_cast(float, (u).w & 0xffff0000u); \
} while (0)

// ---------- prep_k (R4-verified: 1092 blocks) ----------
// [0,512): edge bucketing, 4 edges/thread, batch = bx&7 (XCD-affine with agg).
//          dcnt line-padded: one counter per 64B line.
// [512,1024): cast x -> Xb bf16, 4 x uint4/thread, batch-affine.
// [1024,1092): WT3 fragment-major swizzle: each MFMA B-frag = ONE contiguous 1KB wave-load.
__global__ __launch_bounds__(256) void prep_k(const void* __restrict__ x,
                                              const void* __restrict__ relw,
                                              const void* __restrict__ rootw,
                                              const int* __restrict__ ei,
                                              const int* __restrict__ et,
                                              ushort_t* __restrict__ Xb,
                                              ushort_t* __restrict__ WT3,
                                              int* __restrict__ dcnt,
                                              int* __restrict__ bucket,
                                              int isbf, int w64i, int w64t) {
    int bx = blockIdx.x, t = threadIdx.x;
    if (bx < 512) {                        // ---- edge path ----
        int b = bx & 7;                    // batch -> XCD affinity
        #pragma unroll
        for (int i = 0; i < 4; ++i) {
            int e = (bx >> 3) * 1024 + i * 256 + t;     // < EE
            int src = ldi(ei, (b * 2) * EE + e, w64i);
            int dst = ldi(ei, (b * 2 + 1) * EE + e, w64i);
            int r = ldi(et, (b << 16) + e, w64t);
            int gd = (b << 12) + dst;
            int pos = atomicAdd(&dcnt[gd << 4], 1);
            if (pos < BCAP)
                bucket[gd * BCAP + pos] = (((b << 12) + src) << 4) | r;
        }
    } else if (bx < 1024) {                // ---- cast_x, batch-affine ----
        int bx2 = bx - 512;
        int base = (bx2 & 7) * 65536 + (bx2 >> 3) * 256 + t;
        #pragma unroll
        for (int i = 0; i < 4; ++i) {
            int tid = base + i * 16384;                 // < 524288 uint4
            if (isbf) {
                ((uint4*)Xb)[tid] = ((const uint4*)x)[tid];
            } else {
                const float4* xf = (const float4*)x;
                float4 a = xf[2 * tid], b = xf[2 * tid + 1];
                ushort4 o0, o1;
                o0.x = f2b(a.x); o0.y = f2b(a.y); o0.z = f2b(a.z); o0.w = f2b(a.w);
                o1.x = f2b(b.x); o1.y = f2b(b.y); o1.z = f2b(b.z); o1.w = f2b(b.w);
                ((ushort4*)Xb)[2 * tid] = o0; ((ushort4*)Xb)[2 * tid + 1] = o1;
            }
        }
    } else {                               // ---- WT3 fragment-major build ----
        __shared__ ushort_t Ls[128 * 40];  // [c][k] tile of 32 k-rows
        int mb = bx - 1024;                // 0..67
        int mat = mb >> 2, chunk = mb & 3; // pass, 32-k chunk (=ks)
        const void* src = (mat == 16) ? rootw : relw;
        int soff = (mat == 16) ? 0 : mat * 16384;
        int k0 = chunk * 32;
        #pragma unroll
        for (int i = 0; i < 16; ++i) {     // coalesced read: c fast
            int idx = t + i * 256;         // < 4096
            int k = idx >> 7, c = idx & 127;
            Ls[c * 40 + k] = f2b(ldf(src, soff + (k0 + k) * 128 + c, isbf));
        }
        __syncthreads();
        #pragma unroll
        for (int i = 0; i < 2; ++i) {      // frag-major write: contiguous 1KB per frag
            int idx = t + i * 256;         // < 512 = 8 cg x 64 lanes
            int cg = idx >> 6, lane = idx & 63;
            int lrow = lane & 15, lq = lane >> 4;
            uint4 v = *(const uint4*)(&Ls[(cg * 16 + lrow) * 40 + lq * 8]);
            *(uint4*)(WT3 + ((size_t)((mat * 4 + chunk) * 8 + cg)) * 512 + lane * 8) = v;
        }
    }
}

// ---------- agg_k: wave-role specialization (producer/consumer) ----------
// 512 threads = 8 waves. Waves 0-3: MFMA consumers (R4 tile math verbatim —
// 2x2 frags, frag-major contiguous 1KB B-loads). Waves 4-7: gather producers
// (8 threads/node, 4-deep preload) building A[(p+1)&1] while MFMA reads A[p&1].
// Per-pass critical path = max(gather, MFMA) instead of sum; gather stalls are
// hidden by MFMA waves issuing on the same SIMDs. One barrier per pass.
__global__ __launch_bounds__(512, 4) void agg_k(const ushort_t* __restrict__ Xb,
                                                const ushort_t* __restrict__ WT3,
                                                const int* __restrict__ dcnt,
                                                const int* __restrict__ bucket,
                                                const void* __restrict__ bias,
                                                const void* __restrict__ linw,
                                                const void* __restrict__ linb,
                                                void* __restrict__ out,
                                                int isbf) {
    __shared__ int scnt[NT * 16];              // sort-phase counts (2KB)
    __shared__ ushort_t srt[NT * 16 * 16];     // [row][0]=count,[1..15]=srcs (16KB)
    __shared__ ushort_t A[2][NT * ALP];        // double-buffered A-tile (17.4KB)
    __shared__ float red[NT][5];
    int bx = blockIdx.x, t = threadIdx.x;
    int n0 = (bx & 7) * NN + (bx >> 3) * NT;

    scnt[t & 511] = 0;
    __syncthreads();

    // ---- sort: 16 threads/node across all 512 threads ----
    {
        int ns16 = t >> 4, ts16 = t & 15;
        int gn16 = n0 + ns16;
        int nc = dcnt[gn16 << 4]; if (nc > BCAP) nc = BCAP;
        const int* bk = bucket + gn16 * BCAP;
        for (int j = ts16; j < nc; j += 16) {
            int v = bk[j];
            int row = (ns16 << 4) + (v & 15);
            int pos = atomicAdd(&scnt[row], 1);
            if (pos < SCE)
                srt[(row << 4) + 1 + pos] = (ushort_t)((unsigned)v >> 4);
        }
    }
    __syncthreads();
    srt[t << 4] = (ushort_t)scnt[t];           // fold counts into srt slot 0 (512 rows)
    __syncthreads();

    int wave = t >> 6, lane = t & 63, lrow = lane & 15, lq = lane >> 4;
    int tg = t & 255;                          // gather-role thread index
    int nsub = tg >> 3, tsub = tg & 7;         // node-in-tile, 8 threads/node
    int gn = n0 + nsub;
    int offA = tsub * 8, offB = 64 + tsub * 8;
    f32x4 acc[2][2] = {};

    // prologue: gather waves build A[0] for relation 0 (MFMA waves idle)
    if (wave >= 4) {
        int row = nsub << 4;
        uint4 q0 = *(const uint4*)(&srt[row << 4]);
        int cf = q0.x & 0xffffu; int ce = cf > SCE ? SCE : cf;
        float s[16];
        #pragma unroll
        for (int j = 0; j < 16; ++j) s[j] = 0.f;
        for (int e = 0; e < ce; ++e) {
            int gs = srt[(row << 4) + 1 + e];
            const ushort_t* xr = Xb + (size_t)gs * 128;
            uint4 ua = *(const uint4*)(xr + offA), ub = *(const uint4*)(xr + offB);
            GSUM8(ua, 0); GSUM8(ub, 8);
        }
        float w = (cf > 0) ? 1.0f / (float)cf : 0.f;
        uint4 va, vb;
        va.x = cvtpk(s[0] * w, s[1] * w);   va.y = cvtpk(s[2] * w, s[3] * w);
        va.z = cvtpk(s[4] * w, s[5] * w);   va.w = cvtpk(s[6] * w, s[7] * w);
        vb.x = cvtpk(s[8] * w, s[9] * w);   vb.y = cvtpk(s[10] * w, s[11] * w);
        vb.z = cvtpk(s[12] * w, s[13] * w); vb.w = cvtpk(s[14] * w, s[15] * w);
        *(uint4*)(&A[0][nsub * ALP + offA]) = va;
        *(uint4*)(&A[0][nsub * ALP + offB]) = vb;
    }
    __syncthreads();

    for (int p = 0; p < 17; ++p) {
        int np = p + 1;
        if (wave < 4) {
            // ---- consumer: MFMA on A[p&1]; B-frags = contiguous 1KB L2 loads ----
            const ushort_t* Ap = A[p & 1];
            const ushort_t* bw = WT3 + (size_t)p * 16384 + (wave * 2) * 512 + lane * 8;
            __builtin_amdgcn_s_setprio(1);
            #pragma unroll
            for (int ks = 0; ks < 4; ++ks) {
                int k0 = ks * 32 + lq * 8;
                bf16x8 a0 = *(const bf16x8*)(&Ap[lrow * ALP + k0]);
                bf16x8 a1 = *(const bf16x8*)(&Ap[(16 + lrow) * ALP + k0]);
                bf16x8 b0 = *(const bf16x8*)(bw + ks * 4096);
                bf16x8 b1 = *(const bf16x8*)(bw + ks * 4096 + 512);
                acc[0][0] = __builtin_amdgcn_mfma_f32_16x16x32_bf16(a0, b0, acc[0][0], 0, 0, 0);
                acc[0][1] = __builtin_amdgcn_mfma_f32_16x16x32_bf16(a0, b1, acc[0][1], 0, 0, 0);
                acc[1][0] = __builtin_amdgcn_mfma_f32_16x16x32_bf16(a1, b0, acc[1][0], 0, 0, 0);
                acc[1][1] = __builtin_amdgcn_mfma_f32_16x16x32_bf16(a1, b1, acc[1][1], 0, 0, 0);
            }
            __builtin_amdgcn_s_setprio(0);
        } else if (np < 16) {
            // ---- producer: build A[np&1] for relation np (4-deep preload) ----
            int row = (nsub << 4) + np;
            uint4 q0 = *(const uint4*)(&srt[row << 4]);
            int cf = q0.x & 0xffffu; int ce = cf > SCE ? SCE : cf;
            int e0 = q0.x >> 16, e1 = q0.y & 0xffffu, e2 = q0.y >> 16, e3 = q0.z & 0xffffu;
            uint4 r0a, r0b, r1a, r1b, r2a, r2b, r3a, r3b;
            if (ce > 0) { const ushort_t* xr = Xb + (size_t)e0 * 128; r0a = *(const uint4*)(xr + offA); r0b = *(const uint4*)(xr + offB); }
            if (ce > 1) { const ushort_t* xr = Xb + (size_t)e1 * 128; r1a = *(const uint4*)(xr + offA); r1b = *(const uint4*)(xr + offB); }
            if (ce > 2) { const ushort_t* xr = Xb + (size_t)e2 * 128; r2a = *(const uint4*)(xr + offA); r2b = *(const uint4*)(xr + offB); }
            if (ce > 3) { const ushort_t* xr = Xb + (size_t)e3 * 128; r3a = *(const uint4*)(xr + offA); r3b = *(const uint4*)(xr + offB); }
            float s[16];
            #pragma unroll
            for (int j = 0; j < 16; ++j) s[j] = 0.f;
            if (ce > 0) { GSUM8(r0a, 0); GSUM8(r0b, 8); }
            if (ce > 1) { GSUM8(r1a, 0); GSUM8(r1b, 8); }
            if (ce > 2) { GSUM8(r2a, 0); GSUM8(r2b, 8); }
            if (ce > 3) { GSUM8(r3a, 0); GSUM8(r3b, 8); }
            if (ce > 4) {                  // rare tail (P~0.4% per list)
                for (int e4 = 4; e4 < ce; ++e4) {
                    int gs = srt[(row << 4) + 1 + e4];
                    const ushort_t* xr = Xb + (size_t)gs * 128;
                    uint4 ta = *(const uint4*)(xr + offA), tb = *(const uint4*)(xr + offB);
                    GSUM8(ta, 0); GSUM8(tb, 8);
                }
            }
            float w = (cf > 0) ? 1.0f / (float)cf : 0.f;
            uint4 va, vb;
            va.x = cvtpk(s[0] * w, s[1] * w);   va.y = cvtpk(s[2] * w, s[3] * w);
            va.z = cvtpk(s[4] * w, s[5] * w);   va.w = cvtpk(s[6] * w, s[7] * w);
            vb.x = cvtpk(s[8] * w, s[9] * w);   vb.y = cvtpk(s[10] * w, s[11] * w);
            vb.z = cvtpk(s[12] * w, s[13] * w); vb.w = cvtpk(s[14] * w, s[15] * w);
            *(uint4*)(&A[np & 1][nsub * ALP + offA]) = va;
            *(uint4*)(&A[np & 1][nsub * ALP + offB]) = vb;
        } else if (np == 16) {
            // ---- producer: root pass = own-row copy ----
            const ushort_t* xr = Xb + (size_t)gn * 128;
            uint4 r0a = *(const uint4*)(xr + offA), r0b = *(const uint4*)(xr + offB);
            *(uint4*)(&A[np & 1][nsub * ALP + offA]) = r0a;
            *(uint4*)(&A[np & 1][nsub * ALP + offB]) = r0b;
        }
        if (p < 16) __syncthreads();
    }

    // Epilogue (waves 0-3 hold acc): relu(acc+bias)*linw, reduce over c
    if (wave < 4) {
        int wn = wave << 5;
        int c0 = wn + lrow, c1 = wn + 16 + lrow;
        float bi0 = ldf(bias, c0, isbf), bi1 = ldf(bias, c1, isbf);
        float lw0 = ldf(linw, c0, isbf), lw1 = ldf(linw, c1, isbf);
        #pragma unroll
        for (int mi = 0; mi < 2; ++mi)
            #pragma unroll
            for (int rg = 0; rg < 4; ++rg) {
                float p = fmaxf(acc[mi][0][rg] + bi0, 0.f) * lw0
                        + fmaxf(acc[mi][1][rg] + bi1, 0.f) * lw1;
                p += __shfl_xor(p, 1, 64);
                p += __shfl_xor(p, 2, 64);
                p += __shfl_xor(p, 4, 64);
                p += __shfl_xor(p, 8, 64);
                if (lrow == 0) red[mi * 16 + lq * 4 + rg][wave] = p;
            }
    }
    __syncthreads();
    if (t < NT) {
        float res = red[t][0] + red[t][1] + red[t][2] + red[t][3] + ldf(linb, 0, isbf);
        if (isbf) ((ushort_t*)out)[n0 + t] = f2b(res);
        else      ((float*)out)[n0 + t] = res;
    }
}

extern "C" void kernel_launch(void* const* d_in, const int* in_sizes, int n_in,
                              void* d_out, int out_size, void* d_ws, size_t ws_size,
                              hipStream_t stream) {
    const void* x     = d_in[0];
    const int*  ei    = (const int*)d_in[1];
    const int*  et    = (const int*)d_in[2];
    const void* relw  = d_in[3];
    const void* rootw = d_in[4];
    const void* bias  = d_in[5];
    const void* linw  = d_in[6];
    const void* linb  = d_in[7];

    // Host-side dtype dispatch from input byte sizes
    int isbf = (in_sizes[0] == BB * NN * CC * 2);        // bf16 features
    int w64i = (in_sizes[1] == BB * 2 * EE * 8);         // int64 edge_index
    int w64t = (in_sizes[2] == BB * EE * 8);             // int64 edge_type

    const size_t WS_NEED = 17334272;
    if (ws_size < WS_NEED) return;

    char* ws = (char*)d_ws;
    ushort_t* Xb     = (ushort_t*)(ws);                       //  8,388,608
    ushort_t* WT3    = (ushort_t*)(ws + 8388608);             //    557,056
    int*      dcnt   = (int*)(ws + 8945664);                  //  2,097,152 (line-padded)
    int*      bucket = (int*)(ws + 11042816);                 //  6,291,456 (32768*48*4)

    hipMemsetAsync(dcnt, 0, 2097152, stream);
    prep_k<<<1092, 256, 0, stream>>>(x, relw, rootw, ei, et, Xb, WT3, dcnt, bucket,
                                     isbf, w64i, w64t);
    agg_k<<<1024, 512, 0, stream>>>(Xb, WT3, dcnt, bucket, bias, linw, linb, d_out, isbf);
}